// Round 1
// 685.222 us; speedup vs baseline: 1.0655x; 1.0655x over previous
//
#include <hip/hip_runtime.h>
#include <math.h>

#define N_NODES   50000
#define N_EDGES   1600000
#define N_HEADS   8
#define IN_DIM    512
#define OUT_DIM   64
#define FEAT_DIM  512            // N_HEADS * OUT_DIM
#define LRELU_A   0.2f
#define M_TILES   391            // ceil(50000/128)
#define M_PAD     (M_TILES*128)  // 50048 rows in xh (tail rows read but never stored)
#define SCAN_BLK  49             // ceil(50000/1024)

typedef __attribute__((ext_vector_type(8))) short bf16x8;
typedef __attribute__((ext_vector_type(4))) float f32x4;

__device__ inline unsigned short f2bf(float f) {
    unsigned int u = __float_as_uint(f);
    u = (u + 0x7FFFu + ((u >> 16) & 1u)) >> 16;   // round-to-nearest-even
    return (unsigned short)u;
}
__device__ inline float bf2f(short s) {
    return __uint_as_float(((unsigned int)(unsigned short)s) << 16);
}

// ---------------------------------------------------------------------------
// x (fp32 [N][512]) -> xh (bf16 [M_PAD][512], rows >= N left as poison; never stored)
// ---------------------------------------------------------------------------
__global__ __launch_bounds__(256) void convert_x(const float* __restrict__ x,
                                                 unsigned short* __restrict__ xh) {
    int i = blockIdx.x * blockDim.x + threadIdx.x;   // float4 index
    if (i >= N_NODES * IN_DIM / 4) return;
    float4 v = ((const float4*)x)[i];
    ushort4 o;
    o.x = f2bf(v.x); o.y = f2bf(v.y); o.z = f2bf(v.z); o.w = f2bf(v.w);
    ((ushort4*)xh)[i] = o;
}

// ---------------------------------------------------------------------------
// W (fp32 [8][512][64]) -> Bt (bf16 [n=512][k=512]), Bt[n][k] = W[n>>6][k][n&63]
// ---------------------------------------------------------------------------
__global__ __launch_bounds__(256) void prep_b(const float* __restrict__ W,
                                              unsigned short* __restrict__ Bt) {
    int t = blockIdx.x * blockDim.x + threadIdx.x;   // t = n*512 + k
    if (t >= FEAT_DIM * IN_DIM) return;
    int n = t >> 9, k = t & 511;
    int h = n >> 6, o = n & 63;
    Bt[t] = f2bf(W[(size_t)h * IN_DIM * OUT_DIM + (size_t)k * OUT_DIM + o]);
}

// ---------------------------------------------------------------------------
// feat_h[m][n] = bf16( sum_k xh[m][k] * Bt[n][k] )
// 128x128 tile, BK=32, 256 threads (4 waves, 2x2 wave grid of 64x64),
// mfma_f32_16x16x32_bf16, global_load_lds width-16 staging.
// ---------------------------------------------------------------------------
__global__ __launch_bounds__(256) void gemm_mfma(const unsigned short* __restrict__ xh,
                                                 const unsigned short* __restrict__ Bt,
                                                 unsigned short* __restrict__ feat_h) {
    __shared__ __align__(16) unsigned short As[128 * 32];  // [m][k], 64 B rows
    __shared__ __align__(16) unsigned short Bs[128 * 32];  // [n][k]
    const int t    = threadIdx.x;
    const int wid  = t >> 6;
    const int lane = t & 63;
    const int m0   = blockIdx.x * 128;
    const int n0   = blockIdx.y * 128;
    const int wm   = (wid >> 1) * 64;
    const int wn   = (wid & 1) * 64;
    const int mr   = lane & 15;
    const int q    = lane >> 4;

    f32x4 acc[4][4];
    #pragma unroll
    for (int i = 0; i < 4; ++i)
        #pragma unroll
        for (int j = 0; j < 4; ++j) acc[i][j] = 0.0f;

    const char* xb = (const char*)xh;
    const char* bb = (const char*)Bt;
    const int o1 = t * 16;         const int row1 = o1 >> 6, kb1 = o1 & 63;
    const int o2 = t * 16 + 4096;  const int row2 = o2 >> 6, kb2 = o2 & 63;
    char* lA1 = ((char*)As) + wid * 1024;
    char* lA2 = ((char*)As) + 4096 + wid * 1024;
    char* lB1 = ((char*)Bs) + wid * 1024;
    char* lB2 = ((char*)Bs) + 4096 + wid * 1024;

    for (int k0 = 0; k0 < IN_DIM; k0 += 32) {
        const int kbyte = k0 * 2;
        __builtin_amdgcn_global_load_lds(
            (const __attribute__((address_space(1))) unsigned int*)(xb + (size_t)(m0 + row1) * (IN_DIM * 2) + kbyte + kb1),
            (__attribute__((address_space(3))) unsigned int*)lA1, 16, 0, 0);
        __builtin_amdgcn_global_load_lds(
            (const __attribute__((address_space(1))) unsigned int*)(xb + (size_t)(m0 + row2) * (IN_DIM * 2) + kbyte + kb2),
            (__attribute__((address_space(3))) unsigned int*)lA2, 16, 0, 0);
        __builtin_amdgcn_global_load_lds(
            (const __attribute__((address_space(1))) unsigned int*)(bb + (size_t)(n0 + row1) * (IN_DIM * 2) + kbyte + kb1),
            (__attribute__((address_space(3))) unsigned int*)lB1, 16, 0, 0);
        __builtin_amdgcn_global_load_lds(
            (const __attribute__((address_space(1))) unsigned int*)(bb + (size_t)(n0 + row2) * (IN_DIM * 2) + kbyte + kb2),
            (__attribute__((address_space(3))) unsigned int*)lB2, 16, 0, 0);
        __syncthreads();

        bf16x8 a[4], b[4];
        #pragma unroll
        for (int i = 0; i < 4; ++i)
            a[i] = *(const bf16x8*)&As[(wm + i * 16 + mr) * 32 + q * 8];
        #pragma unroll
        for (int j = 0; j < 4; ++j)
            b[j] = *(const bf16x8*)&Bs[(wn + j * 16 + mr) * 32 + q * 8];
        #pragma unroll
        for (int i = 0; i < 4; ++i)
            #pragma unroll
            for (int j = 0; j < 4; ++j)
                acc[i][j] = __builtin_amdgcn_mfma_f32_16x16x32_bf16(a[i], b[j], acc[i][j], 0, 0, 0);
        __syncthreads();
    }

    #pragma unroll
    for (int i = 0; i < 4; ++i) {
        #pragma unroll
        for (int j = 0; j < 4; ++j) {
            int col = n0 + wn + j * 16 + mr;
            #pragma unroll
            for (int r = 0; r < 4; ++r) {
                int row = m0 + wm + i * 16 + q * 4 + r;
                if (row < N_NODES)
                    feat_h[(size_t)row * FEAT_DIM + col] = f2bf(acc[i][j][r]);
            }
        }
    }
}

// ---------------------------------------------------------------------------
// alpha projections from bf16 feat. One wave per node (all 8 heads).
// ---------------------------------------------------------------------------
__global__ __launch_bounds__(256) void alpha_kernel(const unsigned short* __restrict__ feat_h,
                                                    const float* __restrict__ att_w,
                                                    float* __restrict__ alpha_s,
                                                    float* __restrict__ alpha_d) {
    int node = (blockIdx.x * blockDim.x + threadIdx.x) >> 6;
    int lane = threadIdx.x & 63;
    if (node >= N_NODES) return;
    int h   = lane >> 3;
    int sub = lane & 7;
    bf16x8 f = *(const bf16x8*)&feat_h[(size_t)node * FEAT_DIM + lane * 8];
    float s = 0.f, d = 0.f;
    #pragma unroll
    for (int i = 0; i < 8; ++i) {
        float fv = bf2f(f[i]);
        s += fv * att_w[h * 128 + sub * 8 + i];
        d += fv * att_w[h * 128 + 64 + sub * 8 + i];
    }
    #pragma unroll
    for (int off = 1; off < 8; off <<= 1) {
        s += __shfl_xor(s, off);
        d += __shfl_xor(d, off);
    }
    if (sub == 0) {
        alpha_s[node * N_HEADS + h] = s;
        alpha_d[node * N_HEADS + h] = d;
    }
}

// ---------------------------------------------------------------------------
// CSR build: vectorized count + 3-kernel multi-block scan + vectorized scatter
// ---------------------------------------------------------------------------
__global__ __launch_bounds__(256) void count_kernel(const int* __restrict__ src,
                                                    int* __restrict__ cnt) {
    int e = (blockIdx.x * blockDim.x + threadIdx.x) * 4;
    if (e < N_EDGES) {
        int4 s = *(const int4*)&src[e];
        atomicAdd(&cnt[s.x], 1);
        atomicAdd(&cnt[s.y], 1);
        atomicAdd(&cnt[s.z], 1);
        atomicAdd(&cnt[s.w], 1);
    }
}

__global__ __launch_bounds__(1024) void scan_block_sums(const int* __restrict__ cnt,
                                                        int* __restrict__ partials) {
    __shared__ int wsum[16];
    const int t    = threadIdx.x;
    const int lane = t & 63;
    const int wid  = t >> 6;
    int i = blockIdx.x * 1024 + t;
    int v = (i < N_NODES) ? cnt[i] : 0;
    #pragma unroll
    for (int off = 32; off > 0; off >>= 1) v += __shfl_xor(v, off);
    if (lane == 0) wsum[wid] = v;
    __syncthreads();
    if (t < 16) {
        int u = wsum[t];
        #pragma unroll
        for (int off = 1; off < 16; off <<= 1) u += __shfl_xor(u, off);
        if (t == 0) partials[blockIdx.x] = u;
    }
}

__global__ __launch_bounds__(64) void scan_partials(const int* __restrict__ partials,
                                                    int* __restrict__ blkoff,
                                                    int* __restrict__ row_ptr) {
    int l = threadIdx.x;
    int v = (l < SCAN_BLK) ? partials[l] : 0;
    int incl = v;
    #pragma unroll
    for (int off = 1; off < 64; off <<= 1) {
        int u = __shfl_up(incl, off);
        if (l >= off) incl += u;
    }
    if (l < SCAN_BLK) blkoff[l] = incl - v;
    if (l == SCAN_BLK - 1) row_ptr[N_NODES] = incl;
}

__global__ __launch_bounds__(1024) void scan_apply(const int* __restrict__ cnt,
                                                   const int* __restrict__ blkoff,
                                                   int* __restrict__ row_ptr,
                                                   int* __restrict__ cursor) {
    __shared__ int wsum[16];
    const int t    = threadIdx.x;
    const int lane = t & 63;
    const int wid  = t >> 6;
    int i = blockIdx.x * 1024 + t;
    int v = (i < N_NODES) ? cnt[i] : 0;
    int incl = v;
    #pragma unroll
    for (int off = 1; off < 64; off <<= 1) {
        int u = __shfl_up(incl, off);
        if (lane >= off) incl += u;
    }
    if (lane == 63) wsum[wid] = incl;
    __syncthreads();
    if (t < 16) {
        int u = wsum[t];
        #pragma unroll
        for (int off = 1; off < 16; off <<= 1) {
            int w = __shfl_up(u, off);
            if (t >= off) u += w;
        }
        wsum[t] = u;
    }
    __syncthreads();
    int woff = (wid > 0) ? wsum[wid - 1] : 0;
    int excl = blkoff[blockIdx.x] + woff + incl - v;
    if (i < N_NODES) { row_ptr[i] = excl; cursor[i] = excl; }
}

__global__ __launch_bounds__(256) void scatter_kernel(const int* __restrict__ src,
                                                      const int* __restrict__ dst,
                                                      int* __restrict__ cursor,
                                                      int* __restrict__ csr_dst) {
    int e = (blockIdx.x * blockDim.x + threadIdx.x) * 4;
    if (e < N_EDGES) {
        int4 s = *(const int4*)&src[e];
        int4 d = *(const int4*)&dst[e];
        int p0 = atomicAdd(&cursor[s.x], 1); csr_dst[p0] = d.x;
        int p1 = atomicAdd(&cursor[s.y], 1); csr_dst[p1] = d.y;
        int p2 = atomicAdd(&cursor[s.z], 1); csr_dst[p2] = d.z;
        int p3 = atomicAdd(&cursor[s.w], 1); csr_dst[p3] = d.w;
    }
}

// ---------------------------------------------------------------------------
// Fused single-pass attention+aggregation.
// TWO waves per node (edge-range split, LDS pair-reduce) for 2x parallelism,
// unroll-8 per wave (8 KB of gathers in flight) for 2x MLP per wave.
// Wave-id / node / CSR indices forced uniform via readfirstlane so the edge
// index loads become scalar s_loads (off the vector-memory path).
// Unnormalized accumulation (e^m cancels; |z| small, exp safe in fp32).
// ---------------------------------------------------------------------------
__global__ __launch_bounds__(256) void agg_kernel(const unsigned short* __restrict__ feat_h,
                                                  const float* __restrict__ alpha_s,
                                                  const float* __restrict__ alpha_d,
                                                  const int* __restrict__ row_ptr,
                                                  const int* __restrict__ csr_dst,
                                                  float* __restrict__ out) {
    __shared__ float red[2][64][9];
    const int wv   = __builtin_amdgcn_readfirstlane(threadIdx.x >> 6);  // 0..3, uniform
    const int lane = threadIdx.x & 63;
    const int node = blockIdx.x * 2 + (wv >> 1);   // uniform (N_NODES even: all valid)
    const int half = wv & 1;                       // uniform
    const int h    = lane >> 3;

    const int start = row_ptr[node];
    const int end   = row_ptr[node + 1];
    const int deg   = end - start;
    const int lo    = start + ((deg * half) >> 1);
    const int hi    = start + ((deg * (half + 1)) >> 1);
    const int cnt2  = hi - lo;
    const float as  = alpha_s[node * N_HEADS + h];
    const int* cd   = csr_dst + lo;                // uniform pointer -> s_load

    float sacc = 0.f;
    float acc[8] = {};

    int j = 0;
    for (; j + 8 <= cnt2; j += 8) {
        int d[8];
        #pragma unroll
        for (int k = 0; k < 8; ++k) d[k] = cd[j + k];
        float ad[8];
        #pragma unroll
        for (int k = 0; k < 8; ++k) ad[k] = alpha_d[(size_t)d[k] * N_HEADS + h];
        bf16x8 f[8];
        #pragma unroll
        for (int k = 0; k < 8; ++k)
            f[k] = *(const bf16x8*)&feat_h[(size_t)d[k] * FEAT_DIM + lane * 8];
        float e[8];
        #pragma unroll
        for (int k = 0; k < 8; ++k) {
            float z = as + ad[k];
            z = z > 0.f ? z : LRELU_A * z;
            e[k] = __expf(z);
        }
        sacc += ((e[0] + e[1]) + (e[2] + e[3])) + ((e[4] + e[5]) + (e[6] + e[7]));
        #pragma unroll
        for (int i = 0; i < 8; ++i) {
            float a = acc[i];
            #pragma unroll
            for (int k = 0; k < 8; ++k) a += e[k] * bf2f(f[k][i]);
            acc[i] = a;
        }
    }
    for (; j < cnt2; ++j) {
        int dd = cd[j];
        float ad0 = alpha_d[(size_t)dd * N_HEADS + h];
        bf16x8 f0 = *(const bf16x8*)&feat_h[(size_t)dd * FEAT_DIM + lane * 8];
        float z = as + ad0; z = z > 0.f ? z : LRELU_A * z;
        float e0 = __expf(z);
        sacc += e0;
        #pragma unroll
        for (int i = 0; i < 8; ++i) acc[i] += e0 * bf2f(f0[i]);
    }

    const int pr = wv >> 1;
    if (half == 1) {
        #pragma unroll
        for (int i = 0; i < 8; ++i) red[pr][lane][i] = acc[i];
        red[pr][lane][8] = sacc;
    }
    __syncthreads();
    if (half == 0) {
        #pragma unroll
        for (int i = 0; i < 8; ++i) acc[i] += red[pr][lane][i];
        sacc += red[pr][lane][8];
        const float inv = (deg > 0) ? 1.f / sacc : 0.f;
        f32x4 o0 = { fmaxf(acc[0] * inv, 0.f), fmaxf(acc[1] * inv, 0.f),
                     fmaxf(acc[2] * inv, 0.f), fmaxf(acc[3] * inv, 0.f) };
        f32x4 o1 = { fmaxf(acc[4] * inv, 0.f), fmaxf(acc[5] * inv, 0.f),
                     fmaxf(acc[6] * inv, 0.f), fmaxf(acc[7] * inv, 0.f) };
        f32x4* op = (f32x4*)(out + (size_t)node * FEAT_DIM + lane * 8);
        __builtin_nontemporal_store(o0, op);
        __builtin_nontemporal_store(o1, op + 1);
    }
}

// ---------------------------------------------------------------------------
extern "C" void kernel_launch(void* const* d_in, const int* in_sizes, int n_in,
                              void* d_out, int out_size, void* d_ws, size_t ws_size,
                              hipStream_t stream) {
    const float* x     = (const float*)d_in[0];
    const float* W     = (const float*)d_in[1];
    const float* att_w = (const float*)d_in[2];
    const int*   src   = (const int*)d_in[3];
    const int*   dst   = (const int*)d_in[4];
    float* out = (float*)d_out;

    char* ws = (char*)d_ws;
    size_t off = 0;
    auto alloc = [&](size_t bytes) {
        void* p = ws + off;
        off += (bytes + 255) & ~(size_t)255;
        return p;
    };
    unsigned short* feat_h = (unsigned short*)alloc((size_t)N_NODES * FEAT_DIM * sizeof(short)); // 51.2 MB
    unsigned short* xh     = (unsigned short*)alloc((size_t)M_PAD * IN_DIM * sizeof(short));     // 51.2 MB
    unsigned short* Bt     = (unsigned short*)alloc((size_t)FEAT_DIM * IN_DIM * sizeof(short));  // 0.5 MB
    float* alpha_s = (float*)alloc((size_t)N_NODES * N_HEADS * sizeof(float));
    float* alpha_d = (float*)alloc((size_t)N_NODES * N_HEADS * sizeof(float));
    int*   cnt     = (int*)alloc((size_t)N_NODES * sizeof(int));
    int*   row_ptr = (int*)alloc((size_t)(N_NODES + 1) * sizeof(int));
    int*   cursor  = (int*)alloc((size_t)N_NODES * sizeof(int));
    int*   csr_dst = (int*)alloc((size_t)N_EDGES * sizeof(int));
    int*   partials = (int*)alloc((size_t)SCAN_BLK * sizeof(int));
    int*   blkoff   = (int*)alloc((size_t)SCAN_BLK * sizeof(int));

    (void)hipMemsetAsync(cnt, 0, (size_t)N_NODES * sizeof(int), stream);

    convert_x<<<(N_NODES * IN_DIM / 4 + 255) / 256, 256, 0, stream>>>(x, xh);
    prep_b<<<(FEAT_DIM * IN_DIM + 255) / 256, 256, 0, stream>>>(W, Bt);

    dim3 ggrid(M_TILES, FEAT_DIM / 128);
    gemm_mfma<<<ggrid, 256, 0, stream>>>(xh, Bt, feat_h);

    alpha_kernel<<<(N_NODES + 3) / 4, 256, 0, stream>>>(feat_h, att_w, alpha_s, alpha_d);

    count_kernel<<<(N_EDGES / 4 + 255) / 256, 256, 0, stream>>>(src, cnt);
    scan_block_sums<<<SCAN_BLK, 1024, 0, stream>>>(cnt, partials);
    scan_partials<<<1, 64, 0, stream>>>(partials, blkoff, row_ptr);
    scan_apply<<<SCAN_BLK, 1024, 0, stream>>>(cnt, blkoff, row_ptr, cursor);
    scatter_kernel<<<(N_EDGES / 4 + 255) / 256, 256, 0, stream>>>(src, dst, cursor, csr_dst);

    agg_kernel<<<N_NODES / 2, 256, 0, stream>>>(feat_h, alpha_s, alpha_d, row_ptr, csr_dst, out);
}